// Round 1
// baseline (750.365 us; speedup 1.0000x reference)
//
#include <hip/hip_runtime.h>

// upfirdn2d UP=2, DOWN=1, KS=4, pad=(1,2). Input (16,128,128,128) f32 NCHW.
// GATHER form: out[oy][ox] depends on the 2x2 input quad at (p=oy>>1, q=ox>>1):
//   even ox -> horizontal taps (k1,k3) on x[.][q], x[.][q+1]
//   odd  ox -> horizontal taps (k0,k2)   (same pattern vertically for oy)
// combined 2D weights read directly from the 4x4 outer-product kernel K:
//   oy even: rows (K[1][*], K[3][*]);  oy odd: rows (K[0][*], K[2][*])
//   ox even: cols 1,3;                 ox odd: cols 0,2
// One block per (nc, p): stage input rows p and p+1 (512B each) in LDS,
// thread t = ox writes out[2p][ox] and out[2p+1][ox] -> fully contiguous
// row stores (no stride-2 partial-line writes, no write-allocate fetch).

#define IH 128
#define IW 128

__global__ __launch_bounds__(256) void blur_up2_gather(
    const float* __restrict__ in, const float* __restrict__ ker,
    float* __restrict__ out, int oh, int ow) {
    // XCD-aware swizzle: consecutive LOGICAL blocks (same nc, adjacent p,
    // sharing an input row) land on the same XCD's L2. gridDim % 8 == 0.
    int nwg = gridDim.x;
    int cpx = nwg >> 3;
    int bid = blockIdx.x;
    int lb  = (bid & 7) * cpx + (bid >> 3);

    int p  = lb & 127;   // input row-pair index, 0..127
    int nc = lb >> 7;    // n*C + c, 0..2047

    __shared__ float r0[IW + 4];
    __shared__ float r1[IW + 4];

    int t = threadIdx.x;
    const float* ib = in + (size_t)nc * (IH * IW);
    if (t < IW) {
        r0[t] = ib[(size_t)p * IW + t];               // row p, coalesced 512B
    } else {
        int tt = t - IW;
        r1[tt] = (p + 1 < IH) ? ib[(size_t)(p + 1) * IW + tt] : 0.f;  // row p+1
    }
    if (t == 0) { r0[IW] = 0.f; r1[IW] = 0.f; }       // zero-pad col 128

    // 4x4 kernel, uniform address -> scalar cached broadcast
    float K00 = ker[0],  K01 = ker[1],  K02 = ker[2],  K03 = ker[3];
    float K10 = ker[4],  K11 = ker[5],  K12 = ker[6],  K13 = ker[7];
    float K20 = ker[8],  K21 = ker[9],  K22 = ker[10], K23 = ker[11];
    float K30 = ker[12], K31 = ker[13], K32 = ker[14], K33 = ker[15];

    __syncthreads();

    int ox = t;
    if (ox >= ow) return;          // ow=255: lane 255 idle
    int  q  = ox >> 1;
    bool hx = (ox & 1) != 0;

    float a0 = r0[q], a1 = r0[q + 1];   // row p
    float b0 = r1[q], b1 = r1[q + 1];   // row p+1

    // horizontal parity select (8 cndmasks)
    float w1a = hx ? K10 : K11, w1b = hx ? K12 : K13;   // oy even, row p
    float w3a = hx ? K30 : K31, w3b = hx ? K32 : K33;   // oy even, row p+1
    float w0a = hx ? K00 : K01, w0b = hx ? K02 : K03;   // oy odd,  row p
    float w2a = hx ? K20 : K21, w2b = hx ? K22 : K23;   // oy odd,  row p+1

    float o0 = w1a * a0 + w1b * a1 + w3a * b0 + w3b * b1;  // out[2p][ox]
    float o1 = w0a * a0 + w0b * a1 + w2a * b0 + w2b * b1;  // out[2p+1][ox]

    int oy = 2 * p;                                     // oy < oh always
    size_t ob = (size_t)nc * ((size_t)oh * ow) + (size_t)oy * ow + ox;
    out[ob] = o0;                                       // contiguous row store
    if (oy + 1 < oh) out[ob + ow] = o1;                 // p=127 @ oh=255: skip
}

extern "C" void kernel_launch(void* const* d_in, const int* in_sizes, int n_in,
                              void* d_out, int out_size, void* d_ws, size_t ws_size,
                              hipStream_t stream) {
    const float* imgs = (const float*)d_in[0];
    const float* ker  = (const float*)d_in[1];
    float* out        = (float*)d_out;

    const int NC = 16 * 128;
    int ohw = out_size / NC;                     // OH*OW, square
    int ow = (ohw == 256 * 256) ? 256 : 255;     // hedge 255 vs 256
    int oh = ow;

    int blocks = NC * ((oh + 1) / 2);            // 2048 * 128 = 262144
    blur_up2_gather<<<blocks, 256, 0, stream>>>(imgs, ker, out, oh, ow);
}

// Round 2
// 640.387 us; speedup vs baseline: 1.1717x; 1.1717x over previous
//
#include <hip/hip_runtime.h>

// upfirdn2d UP=2, DOWN=1, KS=4, pad=(1,2). Input (16,128,128,128) f32 NCHW.
// Scatter form with VECTORIZED stores: thread owns input pixels (iy, 2j) and
// (iy, 2j+1); their upsampled outputs are the CONTIGUOUS quad ox=4j..4j+3 on
// rows oy=2iy and 2iy+1 -> two float4 stores (16B/lane, dense 1KB/wave/instr).
//
// Per output quad (ix = 2j and 2j+1), with input
//   a=x[iy][2j], b=x[iy][2j+1], e=x[iy][2j+2]
//   c=x[iy+1][2j], d=x[iy+1][2j+1], f=x[iy+1][2j+2]   (OOB -> 0):
//   out[2iy  ][4j..4j+3] = {K11a+K13b+K31c+K33d, K10a+K12b+K30c+K32d,
//                           K11b+K13e+K31d+K33f, K10b+K12e+K30d+K32f}
//   out[2iy+1][4j..4j+3] = same with K0x/K2x rows (skip if 2iy+1 >= oh).

#define IH 128
#define IW 128

typedef float f2 __attribute__((ext_vector_type(2)));
typedef float f4 __attribute__((ext_vector_type(4)));
typedef f4 uf4 __attribute__((aligned(4)));   // ow=255 -> rows not 16B-aligned

__global__ __launch_bounds__(256) void blur_up2_vec(
    const float* __restrict__ in, const float* __restrict__ ker,
    float* __restrict__ out, int oh, int ow) {
    // XCD swizzle: consecutive logical blocks (adjacent iy, shared boundary
    // row) -> same XCD's L2. gridDim = 65536, %8 == 0 -> bijective.
    int bid = blockIdx.x;
    int lb  = (bid & 7) * (int)(gridDim.x >> 3) + (bid >> 3);
    int id  = lb * 256 + (int)threadIdx.x;

    int j  = id & 63;          // column-pair index: ix = 2j, 2j+1
    int iy = (id >> 6) & 127;
    int nc = id >> 13;         // n*C + c, 0..2047

    const float* ib = in + ((size_t)nc << 14) + ((size_t)iy << 7) + (j << 1);

    f2 r0 = *reinterpret_cast<const f2*>(ib);          // 8B-aligned, coalesced
    float a = r0.x, b = r0.y;
    float e = (j < 63) ? ib[2] : 0.f;                  // L1 hit (neighbor's a)

    float c = 0.f, d = 0.f, f = 0.f;
    if (iy < IH - 1) {
        f2 r1 = *reinterpret_cast<const f2*>(ib + IW);
        c = r1.x; d = r1.y;
        f = (j < 63) ? ib[IW + 2] : 0.f;
    }

    // 4x4 kernel, uniform address -> scalar loads
    float K00 = ker[0],  K01 = ker[1],  K02 = ker[2],  K03 = ker[3];
    float K10 = ker[4],  K11 = ker[5],  K12 = ker[6],  K13 = ker[7];
    float K20 = ker[8],  K21 = ker[9],  K22 = ker[10], K23 = ker[11];
    float K30 = ker[12], K31 = ker[13], K32 = ker[14], K33 = ker[15];

    f4 o0, o1;
    o0.x = K11 * a + K13 * b + K31 * c + K33 * d;
    o0.y = K10 * a + K12 * b + K30 * c + K32 * d;
    o0.z = K11 * b + K13 * e + K31 * d + K33 * f;
    o0.w = K10 * b + K12 * e + K30 * d + K32 * f;
    o1.x = K01 * a + K03 * b + K21 * c + K23 * d;
    o1.y = K00 * a + K02 * b + K20 * c + K22 * d;
    o1.z = K01 * b + K03 * e + K21 * d + K23 * f;
    o1.w = K00 * b + K02 * e + K20 * d + K22 * f;

    int oy = iy << 1, ox = j << 2;
    size_t ob = (size_t)nc * ((size_t)oh * ow) + (size_t)oy * ow + ox;
    bool odd = (oy + 1 < oh);              // uniform per wave (iy const in wave)

    if (ox + 3 < ow) {                     // full quad (all lanes except j=63)
        *reinterpret_cast<uf4*>(out + ob) = o0;
        if (odd) *reinterpret_cast<uf4*>(out + ob + ow) = o1;
    } else {                               // ow=255 tail: cols 252..254 only
        int rem = ow - ox;
        if (rem > 0) out[ob] = o0.x;
        if (rem > 1) out[ob + 1] = o0.y;
        if (rem > 2) out[ob + 2] = o0.z;
        if (odd) {
            if (rem > 0) out[ob + ow] = o1.x;
            if (rem > 1) out[ob + ow + 1] = o1.y;
            if (rem > 2) out[ob + ow + 2] = o1.z;
        }
    }
}

extern "C" void kernel_launch(void* const* d_in, const int* in_sizes, int n_in,
                              void* d_out, int out_size, void* d_ws, size_t ws_size,
                              hipStream_t stream) {
    const float* imgs = (const float*)d_in[0];
    const float* ker  = (const float*)d_in[1];
    float* out        = (float*)d_out;

    const int NC = 16 * 128;
    int ohw = out_size / NC;                     // OH*OW, square
    int ow = (ohw == 256 * 256) ? 256 : 255;     // hedge 255 vs 256
    int oh = ow;

    int total  = NC * IH * (IW / 2);             // 16,777,216 threads
    int blocks = total / 256;                    // 65,536
    blur_up2_vec<<<blocks, 256, 0, stream>>>(imgs, ker, out, oh, ow);
}

// Round 3
// 632.716 us; speedup vs baseline: 1.1859x; 1.0121x over previous
//
#include <hip/hip_runtime.h>

// upfirdn2d UP=2, DOWN=1, KS=4, pad=(1,2). Input (16,128,128,128) f32 NCHW.
// Band-scatter form: thread owns input col-pair (2j,2j+1) x 4 row-pairs
// (input rows 4b..4b+4, top 4 owned + 1 halo). Produces the contiguous
// output quad ox=4j..4j+3 on 8 output rows -> 8 nontemporal float4 stores
// (dense 1020B/wave/instr). Input re-read 1.25x (vs 2x for 1-row-pair),
// nt stores keep the 533MB output stream from thrashing L2.
//
// Per input row y (a=x[y][2j], b=x[y][2j+1], e=x[y][2j+2];
//                  c/d/f = same of row y+1; OOB -> 0):
//   out[2y  ][4j..4j+3] = {K11a+K13b+K31c+K33d, K10a+K12b+K30c+K32d,
//                          K11b+K13e+K31d+K33f, K10b+K12e+K30d+K32f}
//   out[2y+1][4j..4j+3] = same with K0x (row y) / K2x (row y+1) weights.

#define IH 128
#define IW 128

typedef float f2 __attribute__((ext_vector_type(2)));
typedef float f4 __attribute__((ext_vector_type(4)));
typedef f4 uf4 __attribute__((aligned(4)));   // ow=255 -> rows not 16B-aligned

__global__ __launch_bounds__(256) void blur_up2_band(
    const float* __restrict__ in, const float* __restrict__ ker,
    float* __restrict__ out, int oh, int ow) {
    // XCD swizzle: consecutive logical blocks (same nc, adjacent bands that
    // share a halo row) -> same XCD's L2. gridDim = 16384, %8==0 -> bijective.
    int bid = blockIdx.x;
    int lb  = (bid & 7) * (int)(gridDim.x >> 3) + (bid >> 3);
    int id  = lb * 256 + (int)threadIdx.x;

    int j    = id & 63;         // col-pair: ix = 2j, 2j+1
    int band = (id >> 6) & 31;  // input rows 4*band .. 4*band+4
    int nc   = id >> 11;        // n*C + c, 0..2047

    const float* ib = in + ((size_t)nc << 14) + (j << 1);
    int y0 = band << 2;
    bool jin = (j < 63);

    // Load 5 input rows: owned y0..y0+3 plus halo y0+4 (band 31: row 128 -> 0)
    float A[5], B[5], E[5];
#pragma unroll
    for (int r = 0; r < 5; ++r) {
        int y = y0 + r;
        if (y < IH) {
            f2 v = *reinterpret_cast<const f2*>(ib + ((size_t)y << 7));
            A[r] = v.x; B[r] = v.y;
            E[r] = jin ? ib[((size_t)y << 7) + 2] : 0.f;
        } else {
            A[r] = 0.f; B[r] = 0.f; E[r] = 0.f;
        }
    }

    // 4x4 kernel, uniform address -> scalar cached broadcast
    float K00 = ker[0],  K01 = ker[1],  K02 = ker[2],  K03 = ker[3];
    float K10 = ker[4],  K11 = ker[5],  K12 = ker[6],  K13 = ker[7];
    float K20 = ker[8],  K21 = ker[9],  K22 = ker[10], K23 = ker[11];
    float K30 = ker[12], K31 = ker[13], K32 = ker[14], K33 = ker[15];

    size_t obase = (size_t)nc * ((size_t)oh * ow);
    int ox  = j << 2;
    int rem = ow - ox;          // 255-252=3 for j=63, else >=4

#pragma unroll
    for (int k = 0; k < 4; ++k) {
        float a = A[k],     b = B[k],     e = E[k];
        float c = A[k + 1], d = B[k + 1], f = E[k + 1];

        f4 o0, o1;
        o0.x = K11 * a + K13 * b + K31 * c + K33 * d;
        o0.y = K10 * a + K12 * b + K30 * c + K32 * d;
        o0.z = K11 * b + K13 * e + K31 * d + K33 * f;
        o0.w = K10 * b + K12 * e + K30 * d + K32 * f;
        o1.x = K01 * a + K03 * b + K21 * c + K23 * d;
        o1.y = K00 * a + K02 * b + K20 * c + K22 * d;
        o1.z = K01 * b + K03 * e + K21 * d + K23 * f;
        o1.w = K00 * b + K02 * e + K20 * d + K22 * f;

        int oy = (y0 + k) << 1;                  // 2y, always < oh
        size_t ob = obase + (size_t)oy * ow + ox;
        bool odd = (oy + 1 < oh);                // false only y=127 @ oh=255

        if (rem >= 4) {
            __builtin_nontemporal_store(o0, reinterpret_cast<uf4*>(out + ob));
            if (odd)
                __builtin_nontemporal_store(o1, reinterpret_cast<uf4*>(out + ob + ow));
        } else {                                 // ow=255 tail: cols 252..254
            out[ob] = o0.x; out[ob + 1] = o0.y; out[ob + 2] = o0.z;
            if (odd) {
                out[ob + ow] = o1.x; out[ob + ow + 1] = o1.y; out[ob + ow + 2] = o1.z;
            }
        }
    }
}

extern "C" void kernel_launch(void* const* d_in, const int* in_sizes, int n_in,
                              void* d_out, int out_size, void* d_ws, size_t ws_size,
                              hipStream_t stream) {
    const float* imgs = (const float*)d_in[0];
    const float* ker  = (const float*)d_in[1];
    float* out        = (float*)d_out;

    const int NC = 16 * 128;
    int ohw = out_size / NC;                     // OH*OW, square
    int ow = (ohw == 256 * 256) ? 256 : 255;     // hedge 255 vs 256
    int oh = ow;

    int total  = NC * 32 * 64;                   // 4,194,304 threads
    int blocks = total / 256;                    // 16,384
    blur_up2_band<<<blocks, 256, 0, stream>>>(imgs, ker, out, oh, ow);
}